// Round 5
// baseline (16122.020 us; speedup 1.0000x reference)
//
#include <hip/hip_runtime.h>
#include <hip/hip_bf16.h>

// Problem constants: B=2048, T_ENC=96, H=512, T_DEC=48, ATT=14
#define NB 2048
#define NH 512
#define NBLK 256

typedef float f32x4 __attribute__((ext_vector_type(4)));
typedef short bf16x8 __attribute__((ext_vector_type(8)));

__device__ __forceinline__ float sigm(float x) { return 1.0f / (1.0f + __expf(-x)); }
__device__ __forceinline__ float tanhf_(float x) {
  x = fminf(15.0f, fmaxf(-15.0f, x));
  float e = __expf(2.0f * x);
  return (e - 1.0f) / (e + 1.0f);
}

__device__ __forceinline__ void gload_lds16(const ushort* g, ushort* l) {
  __builtin_amdgcn_global_load_lds((const __attribute__((address_space(1))) ushort*)g,
                                   (__attribute__((address_space(3))) ushort*)l, 16, 0, 0);
}

// ---------------- init: fp32->bf16 weight conversion + dec_in0 ----------------
__global__ void init_kernel(const float* __restrict__ WhhE, const float* __restrict__ WhhD,
                            const float* __restrict__ We, const float* __restrict__ Wd,
                            const float* __restrict__ inputs,
                            __hip_bfloat16* __restrict__ oE, __hip_bfloat16* __restrict__ oD,
                            __hip_bfloat16* __restrict__ oWe, __hip_bfloat16* __restrict__ oWd,
                            float* __restrict__ dec_in)
{
  const int NW = 2048 * 512, NS = 512 * 512;
  const int total = 2 * NW + 2 * NS + NB;
  for (int i = blockIdx.x * blockDim.x + threadIdx.x; i < total; i += gridDim.x * blockDim.x) {
    if (i < NW)               oE[i] = __float2bfloat16(WhhE[i]);
    else if (i < 2 * NW)      oD[i - NW] = __float2bfloat16(WhhD[i - NW]);
    else if (i < 2 * NW + NS) oWe[i - 2 * NW] = __float2bfloat16(We[i - 2 * NW]);
    else if (i < 2 * NW + 2 * NS) oWd[i - 2 * NW - NS] = __float2bfloat16(Wd[i - 2 * NW - NS]);
    else { int b = i - 2 * NW - 2 * NS; dec_in[b] = inputs[b * 96 + 95]; }
  }
}

// ---------------- persistent kernel: full seq2seq ----------------
// 256 blocks x 256 threads. 96KB static LDS arena forces 1 block/CU
// (160/96 = 1), so 256 blocks MUST occupy 256 distinct CUs -> co-residency
// guaranteed by construction. LDS buffers addressed via macro offsets
// (pointer-table init of LDS addrs fails to compile on gfx950).
// Block (rb,hb) owns rows rb*128..+128, h-cols hb*32..+32 (all 4 gate
// strips). c-state in registers. Spin loops carry a ~0.5s timeout so a
// pathological schedule produces a wrong answer, not a dead container.
#define LA(b) (smem + (b) * 4096)
#define LB(b) (smem + 8192 + (b) * 4096)
__global__ __launch_bounds__(256, 1) void persist_kernel(
    const float* __restrict__ inputs,
    const ushort* __restrict__ WhhE, const float* __restrict__ encWih, const float* __restrict__ encb,
    const ushort* __restrict__ WhhD, const float* __restrict__ decWih, const float* __restrict__ decb,
    const ushort* __restrict__ WencB, const ushort* __restrict__ WdecB,
    const float* __restrict__ Wval, const float* __restrict__ Wfin, const float* __restrict__ bfin,
    ushort* __restrict__ h0, ushort* __restrict__ h1, float* __restrict__ dec_in,
    float* __restrict__ s_part, float* __restrict__ hdot_part,
    uint* __restrict__ flags, uint* __restrict__ gen,
    float* __restrict__ out)
{
  // 96KB arena; only first 32KB used (2x lA + 2x lB of 8KB each).
  __shared__ __align__(16) ushort smem[49152];

  const int tid = threadIdx.x, lane = tid & 63, w = tid >> 6;
  const int bid = blockIdx.x;
  const int rb = bid >> 4, hb = bid & 15;
  const int kc = lane >> 4, rl = lane & 15;
  uint g = 0;
  ushort* hbuf[2] = {h0, h1};

  // grid barrier: per-block arrival flags + leader-published generation.
  auto gbar = [&]() {
    __syncthreads();
    __threadfence();            // release: write-back this block's global writes
    ++g;
    if (bid == 0) {
      if (tid == 0) __hip_atomic_store(&flags[0], g, __ATOMIC_RELEASE, __HIP_MEMORY_SCOPE_AGENT);
      uint spin = 0;
      while (__hip_atomic_load(&flags[tid], __ATOMIC_ACQUIRE, __HIP_MEMORY_SCOPE_AGENT) < g) {
        __builtin_amdgcn_s_sleep(2);
        if (++spin > 20000000u) break;   // insurance vs container-killing hang
      }
      __builtin_amdgcn_fence(__ATOMIC_ACQUIRE, "agent");
      __syncthreads();
      if (tid == 0) __hip_atomic_store(gen, g, __ATOMIC_RELEASE, __HIP_MEMORY_SCOPE_AGENT);
    } else {
      if (tid == 0) {
        __hip_atomic_store(&flags[bid], g, __ATOMIC_RELEASE, __HIP_MEMORY_SCOPE_AGENT);
        uint spin = 0;
        while (__hip_atomic_load(gen, __ATOMIC_ACQUIRE, __HIP_MEMORY_SCOPE_AGENT) < g) {
          __builtin_amdgcn_s_sleep(2);
          if (++spin > 20000000u) break; // insurance
        }
      }
      __syncthreads();
      __builtin_amdgcn_fence(__ATOMIC_ACQUIRE, "agent");
    }
  };

  float c_reg[2][2][4];   // c-state, matches acc fragment layout: [m][hf][v]
#pragma unroll
  for (int m = 0; m < 2; ++m)
#pragma unroll
    for (int hf = 0; hf < 2; ++hf)
#pragma unroll
      for (int v = 0; v < 4; ++v) c_reg[m][hf][v] = 0.0f;

  // ---- fused LSTM step (gates GEMM + elementwise; optional hdot partials) ----
  auto lstm_phase = [&](const ushort* h_in, ushort* h_out, const ushort* Whh,
                        const float* Wih, const float* bias,
                        const float* xsrc, int xstride, bool dec) {
    f32x4 acc[2][8];
#pragma unroll
    for (int m = 0; m < 2; ++m)
#pragma unroll
      for (int n = 0; n < 8; ++n)
#pragma unroll
        for (int v = 0; v < 4; ++v) acc[m][n][v] = 0.0f;

    auto stage = [&](int buf, int kk) {
      const int k0 = kk * 32;
#pragma unroll
      for (int j = 0; j < 2; ++j) {
        int ps = w * 128 + j * 64 + lane;
        int row = ps >> 2;
        int kc2 = (ps & 3) ^ ((row >> 1) & 3);
        gload_lds16(h_in + (size_t)(rb * 128 + row) * NH + k0 + kc2 * 8,
                    LA(buf) + (w * 128 + j * 64) * 8);
        int wrow = ((row >> 5) * NH) + hb * 32 + (row & 31);
        gload_lds16(Whh + (size_t)wrow * NH + k0 + kc2 * 8,
                    LB(buf) + (w * 128 + j * 64) * 8);
      }
    };
    stage(0, 0);
    __syncthreads();
    int cur = 0;
    for (int kk = 0; kk < 16; ++kk) {
      if (kk < 15) stage(cur ^ 1, kk + 1);
      bf16x8 a[2], b[8];
#pragma unroll
      for (int m = 0; m < 2; ++m) {
        int row = w * 32 + m * 16 + rl;
        a[m] = *(const bf16x8*)(LA(cur) + row * 32 + ((kc ^ ((row >> 1) & 3)) << 3));
      }
#pragma unroll
      for (int n = 0; n < 8; ++n) {
        int j = n * 16 + rl;
        b[n] = *(const bf16x8*)(LB(cur) + j * 32 + ((kc ^ ((j >> 1) & 3)) << 3));
      }
#pragma unroll
      for (int m = 0; m < 2; ++m)
#pragma unroll
        for (int n = 0; n < 8; ++n)
          acc[m][n] = __builtin_amdgcn_mfma_f32_16x16x32_bf16(a[m], b[n], acc[m][n], 0, 0, 0);
      __syncthreads();
      cur ^= 1;
    }

    float xr[2][4];
#pragma unroll
    for (int m = 0; m < 2; ++m)
#pragma unroll
      for (int v = 0; v < 4; ++v) {
        int rg = rb * 128 + w * 32 + m * 16 + kc * 4 + v;
        xr[m][v] = xsrc[(size_t)rg * xstride];
      }
    float hv[2][2][4];
#pragma unroll
    for (int hf = 0; hf < 2; ++hf) {
      int hcol = hb * 32 + hf * 16 + rl;
      float wi0 = Wih[hcol],        bb0 = bias[hcol];
      float wi1 = Wih[512 + hcol],  bb1 = bias[512 + hcol];
      float wi2 = Wih[1024 + hcol], bb2 = bias[1024 + hcol];
      float wi3 = Wih[1536 + hcol], bb3 = bias[1536 + hcol];
#pragma unroll
      for (int m = 0; m < 2; ++m)
#pragma unroll
        for (int v = 0; v < 4; ++v) {
          int rg = rb * 128 + w * 32 + m * 16 + kc * 4 + v;
          float x = xr[m][v];
          float iv = acc[m][0 + hf][v] + x * wi0 + bb0;
          float fv = acc[m][2 + hf][v] + x * wi1 + bb1;
          float gv = acc[m][4 + hf][v] + x * wi2 + bb2;
          float ov = acc[m][6 + hf][v] + x * wi3 + bb3;
          float cold = c_reg[m][hf][v];
          float cn = sigm(fv) * cold + sigm(iv) * tanhf_(gv);
          float hn = sigm(ov) * tanhf_(cn);
          c_reg[m][hf][v] = cn;
          hv[hf][m][v] = hn;
          ((__hip_bfloat16*)h_out)[(size_t)rg * NH + hcol] = __float2bfloat16(hn);
        }
    }
    if (dec) {
      // partial h·Wfin[14:] dot over this block's 32 h-cols
      float wf0 = Wfin[14 + hb * 32 + rl];
      float wf1 = Wfin[14 + hb * 32 + 16 + rl];
#pragma unroll
      for (int m = 0; m < 2; ++m)
#pragma unroll
        for (int v = 0; v < 4; ++v) {
          float hd = hv[0][m][v] * wf0 + hv[1][m][v] * wf1;
#pragma unroll
          for (int msk = 1; msk < 16; msk <<= 1) hd += __shfl_xor(hd, msk);
          if (rl == 0) {
            int rg = rb * 128 + w * 32 + m * 16 + kc * 4 + v;
            hdot_part[hb * NB + rg] = hd;
          }
        }
    }
  };

  // ---- scores GEMM: tanh(hp@We^T + hn@Wd^T), emit partial ·Wval dots ----
  auto scores_phase = [&](const ushort* hp, const ushort* hn) {
    f32x4 acc[2][2];
#pragma unroll
    for (int m = 0; m < 2; ++m)
#pragma unroll
      for (int n = 0; n < 2; ++n)
#pragma unroll
        for (int v = 0; v < 4; ++v) acc[m][n][v] = 0.0f;

    auto stageS = [&](int buf, int kk) {
      const ushort* As = (kk < 16) ? hp : hn;
      const ushort* Bs = (kk < 16) ? WencB : WdecB;
      const int k0 = (kk & 15) * 32;
#pragma unroll
      for (int j = 0; j < 2; ++j) {
        int ps = w * 128 + j * 64 + lane;
        int row = ps >> 2;
        int kc2 = (ps & 3) ^ ((row >> 1) & 3);
        gload_lds16(As + (size_t)(rb * 128 + row) * NH + k0 + kc2 * 8,
                    LA(buf) + (w * 128 + j * 64) * 8);
      }
      if (w < 2) {
        int ps = w * 64 + lane;
        int row = ps >> 2;
        int kc2 = (ps & 3) ^ ((row >> 1) & 3);
        gload_lds16(Bs + (size_t)(hb * 32 + row) * NH + k0 + kc2 * 8,
                    LB(buf) + (w * 64) * 8);
      }
    };
    stageS(0, 0);
    __syncthreads();
    int cur = 0;
    for (int kk = 0; kk < 32; ++kk) {
      if (kk < 31) stageS(cur ^ 1, kk + 1);
      bf16x8 a[2], b[2];
#pragma unroll
      for (int m = 0; m < 2; ++m) {
        int row = w * 32 + m * 16 + rl;
        a[m] = *(const bf16x8*)(LA(cur) + row * 32 + ((kc ^ ((row >> 1) & 3)) << 3));
      }
#pragma unroll
      for (int n = 0; n < 2; ++n) {
        int j = n * 16 + rl;
        b[n] = *(const bf16x8*)(LB(cur) + j * 32 + ((kc ^ ((j >> 1) & 3)) << 3));
      }
#pragma unroll
      for (int m = 0; m < 2; ++m)
#pragma unroll
        for (int n = 0; n < 2; ++n)
          acc[m][n] = __builtin_amdgcn_mfma_f32_16x16x32_bf16(a[m], b[n], acc[m][n], 0, 0, 0);
      __syncthreads();
      cur ^= 1;
    }
    float tv[2][2][4];
#pragma unroll
    for (int m = 0; m < 2; ++m)
#pragma unroll
      for (int n = 0; n < 2; ++n)
#pragma unroll
        for (int v = 0; v < 4; ++v) tv[m][n][v] = tanhf_(acc[m][n][v]);
#pragma unroll 1
    for (int aa = 0; aa < 14; ++aa) {
      float wv0 = Wval[aa * NH + hb * 32 + rl];
      float wv1 = Wval[aa * NH + hb * 32 + 16 + rl];
      float pr[2][4];
#pragma unroll
      for (int m = 0; m < 2; ++m)
#pragma unroll
        for (int v = 0; v < 4; ++v) pr[m][v] = tv[m][0][v] * wv0 + tv[m][1][v] * wv1;
#pragma unroll
      for (int msk = 1; msk < 16; msk <<= 1)
#pragma unroll
        for (int m = 0; m < 2; ++m)
#pragma unroll
          for (int v = 0; v < 4; ++v) pr[m][v] += __shfl_xor(pr[m][v], msk);
      if (rl == aa) {
#pragma unroll
        for (int m = 0; m < 2; ++m)
#pragma unroll
          for (int v = 0; v < 4; ++v) {
            int rg = rb * 128 + w * 32 + m * 16 + kc * 4 + v;
            s_part[((size_t)hb * NB + rg) * 14 + aa] = pr[m][v];
          }
      }
    }
  };

  // ---- finish: combine partials, softmax over 14, write outputs ----
  auto finish_phase = [&](int t) {
    const int row = bid * 8 + (tid >> 5);
    const int sub = tid & 31;
    float s = -1e30f;
    if (sub < 14) {
      s = 0.f;
#pragma unroll 1
      for (int nb2 = 0; nb2 < 16; ++nb2) s += s_part[((size_t)nb2 * NB + row) * 14 + sub];
    }
    float mx = s;
#pragma unroll
    for (int msk = 1; msk < 16; msk <<= 1) mx = fmaxf(mx, __shfl_xor(mx, msk));
    float e = (sub < 14) ? __expf(s - mx) : 0.f;
    float Z = e;
#pragma unroll
    for (int msk = 1; msk < 16; msk <<= 1) Z += __shfl_xor(Z, msk);
    float pa = e / Z;
    float aw = (sub < 14) ? pa * Wfin[sub] : 0.f;
    if (sub < 14) out[NB * 48 + row * 14 + sub] += pa;
#pragma unroll
    for (int msk = 1; msk < 16; msk <<= 1) aw += __shfl_xor(aw, msk);
    float hd = (sub < 16) ? hdot_part[sub * NB + row] : 0.f;
#pragma unroll
    for (int msk = 1; msk < 16; msk <<= 1) hd += __shfl_xor(hd, msk);
    if (sub == 0) {
      float o = aw + hd + bfin[0];
      out[row * 48 + t] = o;
      dec_in[row] = o;
    }
  };

  int p = 0;
#pragma unroll 1
  for (int t = 0; t < 96; ++t) {
    lstm_phase(hbuf[p], hbuf[p ^ 1], WhhE, encWih, encb, inputs + t, 96, false);
    gbar();
    p ^= 1;
  }
#pragma unroll 1
  for (int t = 0; t < 48; ++t) {
    lstm_phase(hbuf[p], hbuf[p ^ 1], WhhD, decWih, decb, dec_in, 1, true);
    gbar();
    scores_phase(hbuf[p], hbuf[p ^ 1]);
    gbar();
    finish_phase(t);
    gbar();
    p ^= 1;
  }
}

extern "C" void kernel_launch(void* const* d_in, const int* in_sizes, int n_in,
                              void* d_out, int out_size, void* d_ws, size_t ws_size,
                              hipStream_t stream)
{
  (void)in_sizes; (void)n_in; (void)out_size; (void)ws_size;
  const float* inputs = (const float*)d_in[0];
  const float* encWih = (const float*)d_in[2];
  const float* encWhh = (const float*)d_in[3];
  const float* encb   = (const float*)d_in[4];
  const float* decWih = (const float*)d_in[5];
  const float* decWhh = (const float*)d_in[6];
  const float* decb   = (const float*)d_in[7];
  const float* Wenc   = (const float*)d_in[8];
  const float* Wdec   = (const float*)d_in[9];
  const float* Wval   = (const float*)d_in[10];
  const float* Wfin   = (const float*)d_in[11];
  const float* bfin   = (const float*)d_in[12];
  float* out = (float*)d_out;
  char* ws = (char*)d_ws;
  const size_t MB = 1 << 20;
  ushort* WhhE_b = (ushort*)(ws + 0);
  ushort* WhhD_b = (ushort*)(ws + 2 * MB);
  ushort* WencB  = (ushort*)(ws + 4 * MB);
  ushort* WdecB  = (ushort*)(ws + 4 * MB + 512 * 1024);
  ushort* hbuf0  = (ushort*)(ws + 5 * MB);
  ushort* hbuf1  = (ushort*)(ws + 7 * MB);
  float*  dec_in = (float*)(ws + 9 * MB);
  float*  s_part = (float*)(ws + 10 * MB);   // 16*2048*14*4 = 1.75 MB
  float*  hdotp  = (float*)(ws + 12 * MB);   // 16*2048*4 = 128 KB
  uint*   flags  = (uint*)(ws + 13 * MB);    // 256 * 4 B
  uint*   gen    = (uint*)(ws + 13 * MB + 4096);

  (void)hipMemsetAsync(hbuf0, 0, 2 * MB, stream);                 // h0 = 0 (bf16 zero)
  (void)hipMemsetAsync(flags, 0, 8192, stream);                   // barrier flags + gen
  (void)hipMemsetAsync(out + 2048 * 48, 0, 2048 * 14 * sizeof(float), stream); // attn accum
  init_kernel<<<1024, 256, 0, stream>>>(encWhh, decWhh, Wenc, Wdec, inputs,
      (__hip_bfloat16*)WhhE_b, (__hip_bfloat16*)WhhD_b,
      (__hip_bfloat16*)WencB, (__hip_bfloat16*)WdecB, dec_in);

  persist_kernel<<<dim3(NBLK), dim3(256), 0, stream>>>(
      inputs,
      WhhE_b, encWih, encb,
      WhhD_b, decWih, decb,
      WencB, WdecB,
      Wval, Wfin, bfin,
      hbuf0, hbuf1, dec_in,
      s_part, hdotp, flags, gen,
      out);
}

// Round 6
// 4454.181 us; speedup vs baseline: 3.6195x; 3.6195x over previous
//
#include <hip/hip_runtime.h>
#include <hip/hip_bf16.h>

// Problem constants: B=2048, T_ENC=96, H=512, T_DEC=48, ATT=14
#define NB 2048
#define NH 512
#define NBLK 256

typedef float f32x4 __attribute__((ext_vector_type(4)));
typedef short bf16x8 __attribute__((ext_vector_type(8)));

__device__ __forceinline__ float sigm(float x) { return 1.0f / (1.0f + __expf(-x)); }
__device__ __forceinline__ float tanhf_(float x) {
  x = fminf(15.0f, fmaxf(-15.0f, x));
  float e = __expf(2.0f * x);
  return (e - 1.0f) / (e + 1.0f);
}

__device__ __forceinline__ void gload_lds16(const ushort* g, ushort* l) {
  __builtin_amdgcn_global_load_lds((const __attribute__((address_space(1))) ushort*)g,
                                   (__attribute__((address_space(3))) ushort*)l, 16, 0, 0);
}

// ---------------- init: fp32->bf16 weight conversion ----------------
__global__ void init_kernel(const float* __restrict__ WhhE, const float* __restrict__ WhhD,
                            const float* __restrict__ We, const float* __restrict__ Wd,
                            __hip_bfloat16* __restrict__ oE, __hip_bfloat16* __restrict__ oD,
                            __hip_bfloat16* __restrict__ oWe, __hip_bfloat16* __restrict__ oWd)
{
  const int NW = 2048 * 512, NS = 512 * 512;
  const int total = 2 * NW + 2 * NS;
  for (int i = blockIdx.x * blockDim.x + threadIdx.x; i < total; i += gridDim.x * blockDim.x) {
    if (i < NW)               oE[i] = __float2bfloat16(WhhE[i]);
    else if (i < 2 * NW)      oD[i - NW] = __float2bfloat16(WhhD[i - NW]);
    else if (i < 2 * NW + NS) oWe[i - 2 * NW] = __float2bfloat16(We[i - 2 * NW]);
    else                      oWd[i - 2 * NW - NS] = __float2bfloat16(Wd[i - 2 * NW - NS]);
  }
}

// ---------------- persistent kernel: full seq2seq ----------------
// 256 blocks x 256 threads. 96KB static LDS arena forces 1 block/CU.
// Block (rb,hb): rows rb*128..+128, h-cols hb*32..+32 (all 4 gate strips).
// ALL cross-block communication is within the 16-block row group (same rb):
// h rows, s_part, hdot_part are row-partitioned. So sync = 16-block
// row-group barrier (leaderless flat poll of 16 flags in one cacheline),
// NOT a 256-block grid barrier (round-5: grid barrier = 65us each, 95% of
// runtime, 1.4GB of poll traffic). Decoder finish is computed redundantly
// per block for its own rows -> x handoff via LDS, no third barrier.
#define LA(b) (smem + (b) * 4096)
#define LB(b) (smem + 8192 + (b) * 4096)
#define XLDS ((float*)(smem + 16384))
__global__ __launch_bounds__(256, 1) void persist_kernel(
    const float* __restrict__ inputs,
    const ushort* __restrict__ WhhE, const float* __restrict__ encWih, const float* __restrict__ encb,
    const ushort* __restrict__ WhhD, const float* __restrict__ decWih, const float* __restrict__ decb,
    const ushort* __restrict__ WencB, const ushort* __restrict__ WdecB,
    const float* __restrict__ Wval, const float* __restrict__ Wfin, const float* __restrict__ bfin,
    ushort* __restrict__ h0, ushort* __restrict__ h1,
    float* __restrict__ s_part, float* __restrict__ hdot_part,
    uint* __restrict__ flags,
    float* __restrict__ out)
{
  __shared__ __align__(16) ushort smem[49152];   // 96KB arena; 32KB tiles + 512B x

  const int tid = threadIdx.x, lane = tid & 63, w = tid >> 6;
  const int bid = blockIdx.x;
  const int rb = bid >> 4, hb = bid & 15;
  const int kc = lane >> 4, rl = lane & 15;
  uint g = 0;
  ushort* hbuf[2] = {h0, h1};

  // 16-block row-group barrier: flat poll, one cacheline of flags per group.
  auto gbar = [&]() {
    __syncthreads();
    ++g;
    if (w == 0) {
      __builtin_amdgcn_fence(__ATOMIC_RELEASE, "agent");   // flush block's writes
      if (lane == 0)
        __hip_atomic_store(&flags[rb * 16 + hb], g, __ATOMIC_RELAXED, __HIP_MEMORY_SCOPE_AGENT);
      const int fidx = rb * 16 + (lane & 15);
      uint spin = 0;
      while (true) {
        uint v = __hip_atomic_load(&flags[fidx], __ATOMIC_RELAXED, __HIP_MEMORY_SCOPE_AGENT);
        if (__all((int)(v >= g))) break;
        __builtin_amdgcn_s_sleep(4);
        if (++spin > 5000000u) break;    // insurance vs container-killing hang
      }
      __builtin_amdgcn_fence(__ATOMIC_ACQUIRE, "agent");   // invalidate stale cache
    }
    __syncthreads();
  };

  float c_reg[2][2][4];   // c-state, matches acc fragment layout: [m][hf][v]
#pragma unroll
  for (int m = 0; m < 2; ++m)
#pragma unroll
    for (int hf = 0; hf < 2; ++hf)
#pragma unroll
      for (int v = 0; v < 4; ++v) c_reg[m][hf][v] = 0.0f;

  float attn_acc[7];      // attn-sum accum: rows rb*128+(tid>>1), a=(tid&1)*7+j
#pragma unroll
  for (int j = 0; j < 7; ++j) attn_acc[j] = 0.0f;

  // ---- fused LSTM step (gates GEMM + elementwise; optional hdot partials) ----
  auto lstm_phase = [&](const ushort* h_in, ushort* h_out, const ushort* Whh,
                        const float* Wih, const float* bias,
                        const float* xsrc, int xstride, bool x_lds, bool dec) {
    f32x4 acc[2][8];
#pragma unroll
    for (int m = 0; m < 2; ++m)
#pragma unroll
      for (int n = 0; n < 8; ++n)
#pragma unroll
        for (int v = 0; v < 4; ++v) acc[m][n][v] = 0.0f;

    auto stage = [&](int buf, int kk) {
      const int k0 = kk * 32;
#pragma unroll
      for (int j = 0; j < 2; ++j) {
        int ps = w * 128 + j * 64 + lane;
        int row = ps >> 2;
        int kc2 = (ps & 3) ^ ((row >> 1) & 3);
        gload_lds16(h_in + (size_t)(rb * 128 + row) * NH + k0 + kc2 * 8,
                    LA(buf) + (w * 128 + j * 64) * 8);
        int wrow = ((row >> 5) * NH) + hb * 32 + (row & 31);
        gload_lds16(Whh + (size_t)wrow * NH + k0 + kc2 * 8,
                    LB(buf) + (w * 128 + j * 64) * 8);
      }
    };
    stage(0, 0);
    __syncthreads();
    int cur = 0;
    for (int kk = 0; kk < 16; ++kk) {
      if (kk < 15) stage(cur ^ 1, kk + 1);
      bf16x8 a[2], b[8];
#pragma unroll
      for (int m = 0; m < 2; ++m) {
        int row = w * 32 + m * 16 + rl;
        a[m] = *(const bf16x8*)(LA(cur) + row * 32 + ((kc ^ ((row >> 1) & 3)) << 3));
      }
#pragma unroll
      for (int n = 0; n < 8; ++n) {
        int j = n * 16 + rl;
        b[n] = *(const bf16x8*)(LB(cur) + j * 32 + ((kc ^ ((j >> 1) & 3)) << 3));
      }
#pragma unroll
      for (int m = 0; m < 2; ++m)
#pragma unroll
        for (int n = 0; n < 8; ++n)
          acc[m][n] = __builtin_amdgcn_mfma_f32_16x16x32_bf16(a[m], b[n], acc[m][n], 0, 0, 0);
      __syncthreads();
      cur ^= 1;
    }

    float xr[2][4];
#pragma unroll
    for (int m = 0; m < 2; ++m)
#pragma unroll
      for (int v = 0; v < 4; ++v) {
        int lr = w * 32 + m * 16 + kc * 4 + v;   // local row 0..127
        xr[m][v] = x_lds ? XLDS[lr] : xsrc[(size_t)(rb * 128 + lr) * xstride];
      }
    float hv[2][2][4];
#pragma unroll
    for (int hf = 0; hf < 2; ++hf) {
      int hcol = hb * 32 + hf * 16 + rl;
      float wi0 = Wih[hcol],        bb0 = bias[hcol];
      float wi1 = Wih[512 + hcol],  bb1 = bias[512 + hcol];
      float wi2 = Wih[1024 + hcol], bb2 = bias[1024 + hcol];
      float wi3 = Wih[1536 + hcol], bb3 = bias[1536 + hcol];
#pragma unroll
      for (int m = 0; m < 2; ++m)
#pragma unroll
        for (int v = 0; v < 4; ++v) {
          int rg = rb * 128 + w * 32 + m * 16 + kc * 4 + v;
          float x = xr[m][v];
          float iv = acc[m][0 + hf][v] + x * wi0 + bb0;
          float fv = acc[m][2 + hf][v] + x * wi1 + bb1;
          float gv = acc[m][4 + hf][v] + x * wi2 + bb2;
          float ov = acc[m][6 + hf][v] + x * wi3 + bb3;
          float cold = c_reg[m][hf][v];
          float cn = sigm(fv) * cold + sigm(iv) * tanhf_(gv);
          float hn = sigm(ov) * tanhf_(cn);
          c_reg[m][hf][v] = cn;
          hv[hf][m][v] = hn;
          ((__hip_bfloat16*)h_out)[(size_t)rg * NH + hcol] = __float2bfloat16(hn);
        }
    }
    if (dec) {
      // partial h·Wfin[14:] dot over this block's 32 h-cols
      float wf0 = Wfin[14 + hb * 32 + rl];
      float wf1 = Wfin[14 + hb * 32 + 16 + rl];
#pragma unroll
      for (int m = 0; m < 2; ++m)
#pragma unroll
        for (int v = 0; v < 4; ++v) {
          float hd = hv[0][m][v] * wf0 + hv[1][m][v] * wf1;
#pragma unroll
          for (int msk = 1; msk < 16; msk <<= 1) hd += __shfl_xor(hd, msk);
          if (rl == 0) {
            int rg = rb * 128 + w * 32 + m * 16 + kc * 4 + v;
            hdot_part[hb * NB + rg] = hd;
          }
        }
    }
  };

  // ---- scores GEMM: tanh(hp@We^T + hn@Wd^T), emit partial ·Wval dots ----
  auto scores_phase = [&](const ushort* hp, const ushort* hn) {
    f32x4 acc[2][2];
#pragma unroll
    for (int m = 0; m < 2; ++m)
#pragma unroll
      for (int n = 0; n < 2; ++n)
#pragma unroll
        for (int v = 0; v < 4; ++v) acc[m][n][v] = 0.0f;

    auto stageS = [&](int buf, int kk) {
      const ushort* As = (kk < 16) ? hp : hn;
      const ushort* Bs = (kk < 16) ? WencB : WdecB;
      const int k0 = (kk & 15) * 32;
#pragma unroll
      for (int j = 0; j < 2; ++j) {
        int ps = w * 128 + j * 64 + lane;
        int row = ps >> 2;
        int kc2 = (ps & 3) ^ ((row >> 1) & 3);
        gload_lds16(As + (size_t)(rb * 128 + row) * NH + k0 + kc2 * 8,
                    LA(buf) + (w * 128 + j * 64) * 8);
      }
      if (w < 2) {
        int ps = w * 64 + lane;
        int row = ps >> 2;
        int kc2 = (ps & 3) ^ ((row >> 1) & 3);
        gload_lds16(Bs + (size_t)(hb * 32 + row) * NH + k0 + kc2 * 8,
                    LB(buf) + (w * 64) * 8);
      }
    };
    stageS(0, 0);
    __syncthreads();
    int cur = 0;
    for (int kk = 0; kk < 32; ++kk) {
      if (kk < 31) stageS(cur ^ 1, kk + 1);
      bf16x8 a[2], b[2];
#pragma unroll
      for (int m = 0; m < 2; ++m) {
        int row = w * 32 + m * 16 + rl;
        a[m] = *(const bf16x8*)(LA(cur) + row * 32 + ((kc ^ ((row >> 1) & 3)) << 3));
      }
#pragma unroll
      for (int n = 0; n < 2; ++n) {
        int j = n * 16 + rl;
        b[n] = *(const bf16x8*)(LB(cur) + j * 32 + ((kc ^ ((j >> 1) & 3)) << 3));
      }
#pragma unroll
      for (int m = 0; m < 2; ++m)
#pragma unroll
        for (int n = 0; n < 2; ++n)
          acc[m][n] = __builtin_amdgcn_mfma_f32_16x16x32_bf16(a[m], b[n], acc[m][n], 0, 0, 0);
      __syncthreads();
      cur ^= 1;
    }
    float tv[2][2][4];
#pragma unroll
    for (int m = 0; m < 2; ++m)
#pragma unroll
      for (int n = 0; n < 2; ++n)
#pragma unroll
        for (int v = 0; v < 4; ++v) tv[m][n][v] = tanhf_(acc[m][n][v]);
#pragma unroll 1
    for (int aa = 0; aa < 14; ++aa) {
      float wv0 = Wval[aa * NH + hb * 32 + rl];
      float wv1 = Wval[aa * NH + hb * 32 + 16 + rl];
      float pr[2][4];
#pragma unroll
      for (int m = 0; m < 2; ++m)
#pragma unroll
        for (int v = 0; v < 4; ++v) pr[m][v] = tv[m][0][v] * wv0 + tv[m][1][v] * wv1;
#pragma unroll
      for (int msk = 1; msk < 16; msk <<= 1)
#pragma unroll
        for (int m = 0; m < 2; ++m)
#pragma unroll
          for (int v = 0; v < 4; ++v) pr[m][v] += __shfl_xor(pr[m][v], msk);
      if (rl == aa) {
#pragma unroll
        for (int m = 0; m < 2; ++m)
#pragma unroll
          for (int v = 0; v < 4; ++v) {
            int rg = rb * 128 + w * 32 + m * 16 + kc * 4 + v;
            s_part[((size_t)hb * NB + rg) * 14 + aa] = pr[m][v];
          }
      }
    }
  };

  // ---- finish (REDUNDANT per block, own 128 rows): softmax + out + x->LDS ----
  // thread (r2 = tid>>1, half = tid&1): a-range half*7..+7 for row rb*128+r2.
  auto finish_phase = [&](int t) {
    const int r2 = tid >> 1, half = tid & 1;
    const int row = rb * 128 + r2;
    float s[7];
#pragma unroll
    for (int j = 0; j < 7; ++j) s[j] = 0.0f;
#pragma unroll 1
    for (int hb2 = 0; hb2 < 16; ++hb2) {
      const float* sp = s_part + ((size_t)hb2 * NB + row) * 14 + half * 7;
#pragma unroll
      for (int j = 0; j < 7; ++j) s[j] += sp[j];
    }
    float mx7 = s[0];
#pragma unroll
    for (int j = 1; j < 7; ++j) mx7 = fmaxf(mx7, s[j]);
    float mx = fmaxf(mx7, __shfl_xor(mx7, 1));
    float e[7];
    float Z7 = 0.0f;
#pragma unroll
    for (int j = 0; j < 7; ++j) { e[j] = __expf(s[j] - mx); Z7 += e[j]; }
    float Z = Z7 + __shfl_xor(Z7, 1);
    float inv = 1.0f / Z;
    float aw7 = 0.0f;
#pragma unroll
    for (int j = 0; j < 7; ++j) {
      float pa = e[j] * inv;
      attn_acc[j] += pa;
      aw7 += pa * Wfin[half * 7 + j];
    }
    float aw = aw7 + __shfl_xor(aw7, 1);
    float hd8 = 0.0f;
#pragma unroll
    for (int k = 0; k < 8; ++k) hd8 += hdot_part[(half * 8 + k) * NB + row];
    float hd = hd8 + __shfl_xor(hd8, 1);
    float o = aw + hd + bfin[0];
    if (half == 0) {
      XLDS[r2] = o;                              // x for next LSTM step (LDS)
      if (hb == 0) out[row * 48 + t] = o;
    }
  };

  int p = 0;
#pragma unroll 1
  for (int t = 0; t < 96; ++t) {
    lstm_phase(hbuf[p], hbuf[p ^ 1], WhhE, encWih, encb, inputs + t, 96, false, false);
    gbar();
    p ^= 1;
  }
#pragma unroll 1
  for (int t = 0; t < 48; ++t) {
    // t=0: x = inputs[:,95] directly; t>0: x from LDS (finish of t-1)
    lstm_phase(hbuf[p], hbuf[p ^ 1], WhhD, decWih, decb,
               inputs + 95, 96, (t != 0), true);
    gbar();
    scores_phase(hbuf[p], hbuf[p ^ 1]);
    gbar();
    finish_phase(t);
    p ^= 1;
  }

  // dump register-accumulated attn sums (once, by hb==0 blocks)
  if (hb == 0) {
    const int r2 = tid >> 1, half = tid & 1;
    const int row = rb * 128 + r2;
#pragma unroll
    for (int j = 0; j < 7; ++j)
      out[NB * 48 + row * 14 + half * 7 + j] = attn_acc[j];
  }
}

extern "C" void kernel_launch(void* const* d_in, const int* in_sizes, int n_in,
                              void* d_out, int out_size, void* d_ws, size_t ws_size,
                              hipStream_t stream)
{
  (void)in_sizes; (void)n_in; (void)out_size; (void)ws_size;
  const float* inputs = (const float*)d_in[0];
  const float* encWih = (const float*)d_in[2];
  const float* encWhh = (const float*)d_in[3];
  const float* encb   = (const float*)d_in[4];
  const float* decWih = (const float*)d_in[5];
  const float* decWhh = (const float*)d_in[6];
  const float* decb   = (const float*)d_in[7];
  const float* Wenc   = (const float*)d_in[8];
  const float* Wdec   = (const float*)d_in[9];
  const float* Wval   = (const float*)d_in[10];
  const float* Wfin   = (const float*)d_in[11];
  const float* bfin   = (const float*)d_in[12];
  float* out = (float*)d_out;
  char* ws = (char*)d_ws;
  const size_t MB = 1 << 20;
  ushort* WhhE_b = (ushort*)(ws + 0);
  ushort* WhhD_b = (ushort*)(ws + 2 * MB);
  ushort* WencB  = (ushort*)(ws + 4 * MB);
  ushort* WdecB  = (ushort*)(ws + 4 * MB + 512 * 1024);
  ushort* hbuf0  = (ushort*)(ws + 5 * MB);
  ushort* hbuf1  = (ushort*)(ws + 7 * MB);
  float*  s_part = (float*)(ws + 10 * MB);   // 16*2048*14*4 = 1.75 MB
  float*  hdotp  = (float*)(ws + 12 * MB);   // 16*2048*4 = 128 KB
  uint*   flags  = (uint*)(ws + 13 * MB);    // 256 * 4 B (16 groups x 1 cacheline)

  (void)hipMemsetAsync(hbuf0, 0, 2 * MB, stream);   // h0 = 0 (bf16 zero)
  (void)hipMemsetAsync(flags, 0, 4096, stream);     // barrier flags (every call!)
  init_kernel<<<1024, 256, 0, stream>>>(encWhh, decWhh, Wenc, Wdec,
      (__hip_bfloat16*)WhhE_b, (__hip_bfloat16*)WhhD_b,
      (__hip_bfloat16*)WencB, (__hip_bfloat16*)WdecB);

  persist_kernel<<<dim3(NBLK), dim3(256), 0, stream>>>(
      inputs,
      WhhE_b, encWih, encb,
      WhhD_b, decWih, decb,
      WencB, WdecB,
      Wval, Wfin, bfin,
      hbuf0, hbuf1,
      s_part, hdotp, flags,
      out);
}

// Round 9
// 4074.065 us; speedup vs baseline: 3.9572x; 1.0933x over previous
//
#include <hip/hip_runtime.h>
#include <hip/hip_bf16.h>

// Problem constants: B=2048, T_ENC=96, H=512, T_DEC=48, ATT=14
#define NB 2048
#define NH 512
#define NBLK 256

typedef float f32x4 __attribute__((ext_vector_type(4)));
typedef short bf16x8 __attribute__((ext_vector_type(8)));

__device__ __forceinline__ float sigm(float x) { return 1.0f / (1.0f + __expf(-x)); }
__device__ __forceinline__ float tanhf_(float x) {
  x = fminf(15.0f, fmaxf(-15.0f, x));
  float e = __expf(2.0f * x);
  return (e - 1.0f) / (e + 1.0f);
}

__device__ __forceinline__ void gload_lds16(const ushort* g, ushort* l) {
  __builtin_amdgcn_global_load_lds((const __attribute__((address_space(1))) ushort*)g,
                                   (__attribute__((address_space(3))) ushort*)l, 16, 0, 0);
}
// counted vmcnt wait + scheduler fence (rule 18: block code motion across it)
#define VMW(n) do { asm volatile("s_waitcnt vmcnt(" #n ")" ::: "memory"); \
                    __builtin_amdgcn_sched_barrier(0); } while (0)
#define SBAR() do { __builtin_amdgcn_s_barrier(); \
                    __builtin_amdgcn_sched_barrier(0); } while (0)

// ---------------- init: fp32->bf16 weight conversion ----------------
__global__ void init_kernel(const float* __restrict__ WhhE, const float* __restrict__ WhhD,
                            const float* __restrict__ We, const float* __restrict__ Wd,
                            __hip_bfloat16* __restrict__ oE, __hip_bfloat16* __restrict__ oD,
                            __hip_bfloat16* __restrict__ oWe, __hip_bfloat16* __restrict__ oWd)
{
  const int NW = 2048 * 512, NS = 512 * 512;
  const int total = 2 * NW + 2 * NS;
  for (int i = blockIdx.x * blockDim.x + threadIdx.x; i < total; i += gridDim.x * blockDim.x) {
    if (i < NW)               oE[i] = __float2bfloat16(WhhE[i]);
    else if (i < 2 * NW)      oD[i - NW] = __float2bfloat16(WhhD[i - NW]);
    else if (i < 2 * NW + NS) oWe[i - 2 * NW] = __float2bfloat16(We[i - 2 * NW]);
    else                      oWd[i - 2 * NW - NS] = __float2bfloat16(Wd[i - 2 * NW - NS]);
  }
}

// ---------------- persistent kernel: full seq2seq ----------------
// 256 blocks x 256 threads; 129KB LDS -> 1 block/CU -> co-residency.
// Block (rb,hb): rows rb*128..+128, h-cols hb*32..+32 (4 gate strips).
// Coherence protocol = the round-6 VERIFIED one: plain stores; gbar =
// syncthreads + REL fence + flag + poll + ACQ fence + syncthreads.
// GEMM k-loops: BK=128, double-buffered 64KB stages, COUNTED vmcnt
// (never 0 mid-loop) + raw s_barrier pairs — the prefetch stays in
// flight across barriers (round 6 drained it every iter: ~800cy x16).
#define SBUF(b) (smem + (b) * 32768)
#define SB_B(b) (SBUF(b) + 16384)
#define XLDS ((float*)(smem + 65536))
__global__ __launch_bounds__(256, 1) void persist_kernel(
    const float* __restrict__ inputs,
    const ushort* __restrict__ WhhE, const float* __restrict__ encWih, const float* __restrict__ encb,
    const ushort* __restrict__ WhhD, const float* __restrict__ decWih, const float* __restrict__ decb,
    const ushort* __restrict__ WencB, const ushort* __restrict__ WdecB,
    const float* __restrict__ Wval, const float* __restrict__ Wfin, const float* __restrict__ bfin,
    ushort* __restrict__ h0, ushort* __restrict__ h1,
    float* __restrict__ s_part, float* __restrict__ hdotp,
    uint* __restrict__ flags,
    float* __restrict__ out)
{
  __shared__ __align__(16) ushort smem[66048];   // 2x64KB stage bufs + 512B XLDS

  const int tid = threadIdx.x, lane = tid & 63, w = tid >> 6;
  const int bid = blockIdx.x;
  const int rb = bid >> 4, hb = bid & 15;
  const int kc = lane >> 4, rl = lane & 15;
  uint g = 0;
  ushort* hbuf[2] = {h0, h1};

  // 16-block row-group barrier (VERIFIED round-6 protocol, verbatim)
  auto gbar = [&]() {
    __syncthreads();
    ++g;
    if (w == 0) {
      __builtin_amdgcn_fence(__ATOMIC_RELEASE, "agent");   // flush block's writes
      if (lane == 0)
        __hip_atomic_store(&flags[rb * 16 + hb], g, __ATOMIC_RELAXED, __HIP_MEMORY_SCOPE_AGENT);
      const int fidx = rb * 16 + (lane & 15);
      uint spin = 0;
      while (true) {
        uint v = __hip_atomic_load(&flags[fidx], __ATOMIC_RELAXED, __HIP_MEMORY_SCOPE_AGENT);
        if (__all((int)(v >= g))) break;
        __builtin_amdgcn_s_sleep(4);
        if (++spin > 5000000u) break;    // insurance vs container-killing hang
      }
      __builtin_amdgcn_fence(__ATOMIC_ACQUIRE, "agent");   // invalidate stale cache
    }
    __syncthreads();
  };

  float c_reg[2][2][4];   // c-state in registers: [m][hf][v]
#pragma unroll
  for (int m = 0; m < 2; ++m)
#pragma unroll
    for (int hf = 0; hf < 2; ++hf)
#pragma unroll
      for (int v = 0; v < 4; ++v) c_reg[m][hf][v] = 0.0f;

  float attn_acc[7];      // attn-sum accum: row rb*128+(tid>>1), a=(tid&1)*7+j
#pragma unroll
  for (int j = 0; j < 7; ++j) attn_acc[j] = 0.0f;

  // ---- fused LSTM step: gates GEMM (BK=128, 4 iters) + elementwise ----
  auto lstm_phase = [&](const ushort* h_in, ushort* h_out, const ushort* Whh,
                        const float* Wih, const float* bias,
                        const float* xsrc, int xstride, bool x_lds,
                        float* hd_out) {
    __syncthreads();           // clean slate: drain prior stores, LDS visibility

    // x read FIRST (before any staging) so in-loop vmcnt counts stay exact:
    // the xr loads are older than stage(0), so iter-0's VMW(16) drains them.
    float xr[2][4];
#pragma unroll
    for (int m = 0; m < 2; ++m)
#pragma unroll
      for (int v = 0; v < 4; ++v) {
        int lr = w * 32 + m * 16 + kc * 4 + v;
        xr[m][v] = x_lds ? XLDS[lr] : xsrc[(size_t)(rb * 128 + lr) * xstride];
      }

    f32x4 acc[2][8];
#pragma unroll
    for (int m = 0; m < 2; ++m)
#pragma unroll
      for (int n = 0; n < 8; ++n)
#pragma unroll
        for (int v = 0; v < 4; ++v) acc[m][n][v] = 0.0f;

    // stage A (h rows) + B (W gate rows): 16 gload_lds / thread.
    // LDS [row][16 slots of 16B], slot' = slot ^ (row&15) (pre-swz source).
    auto stageAB = [&](int kk, int buf) {
      ushort* A = SBUF(buf); ushort* Bp = SB_B(buf);
#pragma unroll
      for (int j = 0; j < 8; ++j) {
        int gs = (w * 8 + j) * 64 + lane;
        int row = gs >> 4, ds = gs & 15;
        int ss = ds ^ (row & 15);
        gload_lds16(h_in + (size_t)(rb * 128 + row) * NH + kk * 128 + ss * 8,
                    A + (w * 8 + j) * 512);
        int wrow = (row >> 5) * NH + hb * 32 + (row & 31);
        gload_lds16(Whh + (size_t)wrow * NH + kk * 128 + ss * 8,
                    Bp + (w * 8 + j) * 512);
      }
    };

    stageAB(0, 0);
    int cur = 0;
#pragma unroll 1
    for (int kk = 0; kk < 4; ++kk) {
      if (kk < 3) { stageAB(kk + 1, cur ^ 1); VMW(16); }
      else        { VMW(0); }
      SBAR();                      // everyone's stage(kk) complete
      ushort* A = SBUF(cur); ushort* Bp = SB_B(cur);
#pragma unroll
      for (int s = 0; s < 4; ++s) {
        const int qs = ((s * 4 + kc) ^ rl) << 3;
        bf16x8 a[2], b[8];
#pragma unroll
        for (int m = 0; m < 2; ++m)
          a[m] = *(const bf16x8*)(A + (w * 32 + m * 16 + rl) * 128 + qs);
#pragma unroll
        for (int n = 0; n < 8; ++n)
          b[n] = *(const bf16x8*)(Bp + (n * 16 + rl) * 128 + qs);
#pragma unroll
        for (int m = 0; m < 2; ++m)
#pragma unroll
          for (int n = 0; n < 8; ++n)
            acc[m][n] = __builtin_amdgcn_mfma_f32_16x16x32_bf16(a[m], b[n], acc[m][n], 0, 0, 0);
      }
      SBAR();                      // everyone's reads done before next overwrite
      cur ^= 1;
    }

    float hv[2][2][4];
#pragma unroll
    for (int hf = 0; hf < 2; ++hf) {
      int hcol = hb * 32 + hf * 16 + rl;
      float wi0 = Wih[hcol],        bb0 = bias[hcol];
      float wi1 = Wih[512 + hcol],  bb1 = bias[512 + hcol];
      float wi2 = Wih[1024 + hcol], bb2 = bias[1024 + hcol];
      float wi3 = Wih[1536 + hcol], bb3 = bias[1536 + hcol];
#pragma unroll
      for (int m = 0; m < 2; ++m)
#pragma unroll
        for (int v = 0; v < 4; ++v) {
          int rg = rb * 128 + w * 32 + m * 16 + kc * 4 + v;
          float x = xr[m][v];
          float iv = acc[m][0 + hf][v] + x * wi0 + bb0;
          float fv = acc[m][2 + hf][v] + x * wi1 + bb1;
          float gv = acc[m][4 + hf][v] + x * wi2 + bb2;
          float ov = acc[m][6 + hf][v] + x * wi3 + bb3;
          float cold = c_reg[m][hf][v];
          float cn = sigm(fv) * cold + sigm(iv) * tanhf_(gv);
          float hn = sigm(ov) * tanhf_(cn);
          c_reg[m][hf][v] = cn;
          hv[hf][m][v] = hn;
          ((__hip_bfloat16*)h_out)[(size_t)rg * NH + hcol] = __float2bfloat16(hn);
        }
    }
    if (hd_out) {
      float wf0 = Wfin[14 + hb * 32 + rl];
      float wf1 = Wfin[14 + hb * 32 + 16 + rl];
#pragma unroll
      for (int m = 0; m < 2; ++m)
#pragma unroll
        for (int v = 0; v < 4; ++v) {
          float hd = hv[0][m][v] * wf0 + hv[1][m][v] * wf1;
#pragma unroll
          for (int msk = 1; msk < 16; msk <<= 1) hd += __shfl_xor(hd, msk);
          if (rl == 0) {
            int rg = rb * 128 + w * 32 + m * 16 + kc * 4 + v;
            hd_out[hb * NB + rg] = hd;
          }
        }
    }
  };

  // ---- scores: tanh(hp@We^T + hn@Wd^T) -> partial .Wval dots ----
  auto scores_phase = [&](const ushort* hp, const ushort* hn) {
    __syncthreads();
    f32x4 acc[2][2];
#pragma unroll
    for (int m = 0; m < 2; ++m)
#pragma unroll
      for (int n = 0; n < 2; ++n)
#pragma unroll
        for (int v = 0; v < 4; ++v) acc[m][n][v] = 0.0f;

    // stage A (8 ops) + B slice 32 rows (2 ops) = 10 gload_lds / thread
    auto stageS = [&](int kk, int buf) {
      const ushort* As = (kk < 4) ? hp : hn;
      const ushort* Bs = (kk < 4) ? WencB : WdecB;
      const int kc4 = (kk & 3) * 128;
      ushort* A = SBUF(buf); ushort* Bp = SB_B(buf);
#pragma unroll
      for (int j = 0; j < 8; ++j) {
        int gs = (w * 8 + j) * 64 + lane;
        int row = gs >> 4, ds = gs & 15;
        int ss = ds ^ (row & 15);
        gload_lds16(As + (size_t)(rb * 128 + row) * NH + kc4 + ss * 8,
                    A + (w * 8 + j) * 512);
      }
#pragma unroll
      for (int j2 = 0; j2 < 2; ++j2) {
        int gs = (w * 2 + j2) * 64 + lane;
        int row = gs >> 4, ds = gs & 15;
        int ss = ds ^ (row & 15);
        gload_lds16(Bs + (size_t)(hb * 32 + row) * NH + kc4 + ss * 8,
                    Bp + (w * 2 + j2) * 512);
      }
    };

    stageS(0, 0);
    int cur = 0;
#pragma unroll 1
    for (int kk = 0; kk < 8; ++kk) {
      if (kk < 7) { stageS(kk + 1, cur ^ 1); VMW(10); }
      else        { VMW(0); }
      SBAR();
      ushort* A = SBUF(cur); ushort* Bp = SB_B(cur);
#pragma unroll
      for (int s = 0; s < 4; ++s) {
        const int qs = ((s * 4 + kc) ^ rl) << 3;
        bf16x8 a[2], b[2];
#pragma unroll
        for (int m = 0; m < 2; ++m)
          a[m] = *(const bf16x8*)(A + (w * 32 + m * 16 + rl) * 128 + qs);
#pragma unroll
        for (int n = 0; n < 2; ++n)
          b[n] = *(const bf16x8*)(Bp + (n * 16 + rl) * 128 + qs);
#pragma unroll
        for (int m = 0; m < 2; ++m)
#pragma unroll
          for (int n = 0; n < 2; ++n)
            acc[m][n] = __builtin_amdgcn_mfma_f32_16x16x32_bf16(a[m], b[n], acc[m][n], 0, 0, 0);
      }
      SBAR();
      cur ^= 1;
    }

    float tv[2][2][4];
#pragma unroll
    for (int m = 0; m < 2; ++m)
#pragma unroll
      for (int n = 0; n < 2; ++n)
#pragma unroll
        for (int v = 0; v < 4; ++v) tv[m][n][v] = tanhf_(acc[m][n][v]);
#pragma unroll 1
    for (int aa = 0; aa < 14; ++aa) {
      float wv0 = Wval[aa * NH + hb * 32 + rl];
      float wv1 = Wval[aa * NH + hb * 32 + 16 + rl];
      float pr[2][4];
#pragma unroll
      for (int m = 0; m < 2; ++m)
#pragma unroll
        for (int v = 0; v < 4; ++v) pr[m][v] = tv[m][0][v] * wv0 + tv[m][1][v] * wv1;
#pragma unroll
      for (int msk = 1; msk < 16; msk <<= 1)
#pragma unroll
        for (int m = 0; m < 2; ++m)
#pragma unroll
          for (int v = 0; v < 4; ++v) pr[m][v] += __shfl_xor(pr[m][v], msk);
      if (rl == aa) {
#pragma unroll
        for (int m = 0; m < 2; ++m)
#pragma unroll
          for (int v = 0; v < 4; ++v) {
            int rg = rb * 128 + w * 32 + m * 16 + kc * 4 + v;
            s_part[((size_t)hb * NB + rg) * 14 + aa] = pr[m][v];
          }
      }
    }
  };

  // ---- finish (redundant per block, own 128 rows): softmax + out + x->LDS ----
  auto finish_phase = [&](int t, const float* hd_cur) {
    const int r2 = tid >> 1, half = tid & 1;
    const int row = rb * 128 + r2;
    float s[7];
#pragma unroll
    for (int j = 0; j < 7; ++j) s[j] = 0.0f;
#pragma unroll 1
    for (int hb2 = 0; hb2 < 16; ++hb2) {
      const float* sp = s_part + ((size_t)hb2 * NB + row) * 14 + half * 7;
#pragma unroll
      for (int j = 0; j < 7; ++j) s[j] += sp[j];
    }
    float mx7 = s[0];
#pragma unroll
    for (int j = 1; j < 7; ++j) mx7 = fmaxf(mx7, s[j]);
    float mx = fmaxf(mx7, __shfl_xor(mx7, 1));
    float e[7];
    float Z7 = 0.0f;
#pragma unroll
    for (int j = 0; j < 7; ++j) { e[j] = __expf(s[j] - mx); Z7 += e[j]; }
    float Z = Z7 + __shfl_xor(Z7, 1);
    float inv = 1.0f / Z;
    float aw7 = 0.0f;
#pragma unroll
    for (int j = 0; j < 7; ++j) {
      float pa = e[j] * inv;
      attn_acc[j] += pa;
      aw7 += pa * Wfin[half * 7 + j];
    }
    float aw = aw7 + __shfl_xor(aw7, 1);
    float hd8 = 0.0f;
#pragma unroll
    for (int k = 0; k < 8; ++k) hd8 += hd_cur[(half * 8 + k) * NB + row];
    float hd = hd8 + __shfl_xor(hd8, 1);
    float o = aw + hd + bfin[0];
    if (half == 0) {
      XLDS[r2] = o;                              // x for next LSTM step (LDS)
      if (hb == 0) out[row * 48 + t] = o;
    }
  };

  int p = 0;
#pragma unroll 1
  for (int t = 0; t < 96; ++t) {
    lstm_phase(hbuf[p], hbuf[p ^ 1], WhhE, encWih, encb, inputs + t, 96, false, nullptr);
    gbar();
    p ^= 1;
  }
#pragma unroll 1
  for (int t = 0; t < 48; ++t) {
    float* hd_cur = hdotp + (t & 1) * (NB * 16);   // ping-pong: finish(t) vs lstm(t+1)
    lstm_phase(hbuf[p], hbuf[p ^ 1], WhhD, decWih, decb,
               inputs + 95, 96, (t != 0), hd_cur);
    gbar();
    scores_phase(hbuf[p], hbuf[p ^ 1]);
    gbar();
    finish_phase(t, hd_cur);
    p ^= 1;
  }

  // dump register-accumulated attn sums (hb==0 blocks)
  if (hb == 0) {
    const int r2 = tid >> 1, half = tid & 1;
    const int row = rb * 128 + r2;
#pragma unroll
    for (int j = 0; j < 7; ++j)
      out[NB * 48 + row * 14 + half * 7 + j] = attn_acc[j];
  }
}

extern "C" void kernel_launch(void* const* d_in, const int* in_sizes, int n_in,
                              void* d_out, int out_size, void* d_ws, size_t ws_size,
                              hipStream_t stream)
{
  (void)in_sizes; (void)n_in; (void)out_size; (void)ws_size;
  const float* inputs = (const float*)d_in[0];
  const float* encWih = (const float*)d_in[2];
  const float* encWhh = (const float*)d_in[3];
  const float* encb   = (const float*)d_in[4];
  const float* decWih = (const float*)d_in[5];
  const float* decWhh = (const float*)d_in[6];
  const float* decb   = (const float*)d_in[7];
  const float* Wenc   = (const float*)d_in[8];
  const float* Wdec   = (const float*)d_in[9];
  const float* Wval   = (const float*)d_in[10];
  const float* Wfin   = (const float*)d_in[11];
  const float* bfin   = (const float*)d_in[12];
  float* out = (float*)d_out;
  char* ws = (char*)d_ws;
  const size_t MB = 1 << 20;
  ushort* WhhE_b = (ushort*)(ws + 0);
  ushort* WhhD_b = (ushort*)(ws + 2 * MB);
  ushort* WencB  = (ushort*)(ws + 4 * MB);
  ushort* WdecB  = (ushort*)(ws + 4 * MB + 512 * 1024);
  ushort* hbuf0  = (ushort*)(ws + 5 * MB);
  ushort* hbuf1  = (ushort*)(ws + 7 * MB);
  float*  s_part = (float*)(ws + 10 * MB);   // 16*2048*14*4 = 1.75 MB
  float*  hdotp  = (float*)(ws + 12 * MB);   // 2 * 16*2048*4 = 256 KB (ping-pong)
  uint*   flags  = (uint*)(ws + 13 * MB);

  (void)hipMemsetAsync(hbuf0, 0, 2 * MB, stream);   // h0 = 0 (bf16 zero)
  (void)hipMemsetAsync(flags, 0, 4096, stream);     // barrier flags (every call!)
  init_kernel<<<1024, 256, 0, stream>>>(encWhh, decWhh, Wenc, Wdec,
      (__hip_bfloat16*)WhhE_b, (__hip_bfloat16*)WhhD_b,
      (__hip_bfloat16*)WencB, (__hip_bfloat16*)WdecB);

  persist_kernel<<<dim3(NBLK), dim3(256), 0, stream>>>(
      inputs,
      WhhE_b, encWih, encb,
      WhhD_b, decWih, decb,
      WencB, WdecB,
      Wval, Wfin, bfin,
      hbuf0, hbuf1,
      s_part, hdotp, flags,
      out);
}